// Round 3
// baseline (117.754 us; speedup 1.0000x reference)
//
#include <hip/hip_runtime.h>

// WeightedTensorProduct: out[b, seg[k], c] += x1[b,M1[k],c]*x2[b,M2[k],c]*CG[k]*W[l_ind[k],c]
// Structure is a deterministic function of L=3 -> replicated at compile time.
// R3: cg[k] (wave-uniform, runtime values) broadcast via v_readlane from 8 VGPRs
//     loaded once per wave -- removes the 478 serialized s_load/scalar-cache
//     accesses (R1/R2 bottleneck theory). Factorized (mo,triple) form keeps
//     VALU at ~3 ops/entry.

#define LMAX 3
#define MOUT 16          // (L+1)^2
#define CCH 128          // channels
#define NTRI 34
#define NNZ 478
#define NPAIR 156        // nonempty (output-order, triple) pairs
#define NCGV 8           // ceil(NNZ/64) VGPRs holding cg per wave

struct Tables {
    int n_tri = 0;
    int nnz = 0;
    int np = 0;
    int tl[NTRI] = {}, tl1[NTRI] = {}, tl2[NTRI] = {};
    int M1[NNZ] = {}, M2[NNZ] = {};
    int pair_tri[NPAIR] = {};
    int pair_kstart[NPAIR + 1] = {};
    int mo_pstart[MOUT + 1] = {};
};

constexpr Tables build_tables() {
    Tables T{};
    // triples, insertion order == tri_index order in the reference
    for (int l1 = 0; l1 <= LMAX; ++l1) {
        for (int l2 = 0; l2 <= LMAX; ++l2) {
            int lo = l1 - l2; if (lo < 0) lo = -lo;
            int hi = l1 + l2; if (hi > LMAX) hi = LMAX;
            for (int l = lo; l <= hi; ++l) {
                T.tl[T.n_tri] = l; T.tl1[T.n_tri] = l1; T.tl2[T.n_tri] = l2;
                ++T.n_tri;
            }
        }
    }
    // rows sorted by output order Mo; entries grouped by (Mo, triple)
    for (int l = 0; l <= LMAX; ++l) {
        for (int m = -l; m <= l; ++m) {
            const int Mo = l * l + l + m;
            T.mo_pstart[Mo] = T.np;
            for (int t = 0; t < T.n_tri; ++t) {
                if (T.tl[t] != l) continue;
                const int l1 = T.tl1[t], l2 = T.tl2[t];
                int lo = (-l1 > m - l2) ? -l1 : m - l2;
                int hi = (l1 < m + l2) ? l1 : m + l2;
                if (lo > hi) continue;
                T.pair_tri[T.np] = t;
                T.pair_kstart[T.np] = T.nnz;
                ++T.np;
                for (int m1 = lo; m1 <= hi; ++m1) {
                    const int m2 = m - m1;
                    T.M1[T.nnz] = l1 * l1 + l1 + m1;
                    T.M2[T.nnz] = l2 * l2 + l2 + m2;
                    ++T.nnz;
                }
            }
        }
    }
    T.mo_pstart[MOUT] = T.np;
    T.pair_kstart[T.np] = T.nnz;
    return T;
}

constexpr Tables TB = build_tables();
static_assert(TB.nnz == NNZ, "nnz mismatch vs reference _build_structure");
static_assert(TB.n_tri == NTRI, "n_tri mismatch vs reference _build_structure");
static_assert(TB.np == NPAIR, "pair count mismatch");

__global__ __launch_bounds__(256, 4)
void wtp_kernel(const float* __restrict__ x1, const float* __restrict__ x2,
                const float* __restrict__ w, const float* __restrict__ cg,
                float* __restrict__ out, int B) {
    const int c = threadIdx.x;                              // channel 0..127
    const int lane = threadIdx.x & 63;                      // lane within wave
    const int b = blockIdx.x * blockDim.y + threadIdx.y;    // batch
    if (b >= B) return;

    // cg staged across the wave's lanes: vcg[j] lane L holds cg[j*64+L].
    // One coalesced dword load per 64 values; j=7 tail exec-masked.
    float vcg[NCGV];
#pragma unroll
    for (int j = 0; j < NCGV; ++j) {
        const int idx = j * 64 + lane;
        vcg[j] = (idx < NNZ) ? cg[idx] : 0.f;
    }

    const size_t base = (size_t)b * (MOUT * CCH) + c;
    const float* x1b = x1 + base;
    const float* x2b = x2 + base;

    // x1/x2 rows for this (b,c) into registers: coalesced dword loads per wave
    float x1r[MOUT], x2r[MOUT];
#pragma unroll
    for (int m = 0; m < MOUT; ++m) {
        x1r[m] = x1b[(size_t)m * CCH];
        x2r[m] = x2b[(size_t)m * CCH];
    }

    // all 34 per-triple weights for this channel into registers
    float wr[NTRI];
#pragma unroll
    for (int t = 0; t < NTRI; ++t) wr[t] = w[t * CCH + c];

    float* outb = out + base;
#pragma unroll
    for (int mo = 0; mo < MOUT; ++mo) {
        float acc = 0.f;
#pragma unroll
        for (int p = TB.mo_pstart[mo]; p < TB.mo_pstart[mo + 1]; ++p) {
            float inner = 0.f;
#pragma unroll
            for (int k = TB.pair_kstart[p]; k < TB.pair_kstart[p + 1]; ++k) {
                // v_readlane_b32: wave-uniform cg[k] from VGPR lane (both
                // operands compile-time constants) -> SGPR, no SMEM access.
                const float cgk = __int_as_float(
                    __builtin_amdgcn_readlane(__float_as_int(vcg[k >> 6]), k & 63));
                inner = fmaf(cgk, x1r[TB.M1[k]] * x2r[TB.M2[k]], inner);
            }
            acc = fmaf(wr[TB.pair_tri[p]], inner, acc);
        }
        outb[(size_t)mo * CCH] = acc;
    }
}

extern "C" void kernel_launch(void* const* d_in, const int* in_sizes, int n_in,
                              void* d_out, int out_size, void* d_ws, size_t ws_size,
                              hipStream_t stream) {
    const float* x1 = (const float*)d_in[0];
    const float* x2 = (const float*)d_in[1];
    const float* w  = (const float*)d_in[2];
    const float* cg = (const float*)d_in[3];
    float* out = (float*)d_out;

    const int B = in_sizes[0] / (MOUT * CCH);   // 2048

    dim3 block(CCH, 2, 1);                      // 256 threads: lane = channel
    dim3 grid((B + 1) / 2, 1, 1);
    wtp_kernel<<<grid, block, 0, stream>>>(x1, x2, w, cg, out, B);
}

// Round 4
// 117.107 us; speedup vs baseline: 1.0055x; 1.0055x over previous
//
#include <hip/hip_runtime.h>

// WeightedTensorProduct: out[b, seg[k], c] += x1[b,M1[k],c]*x2[b,M2[k],c]*CG[k]*W[l_ind[k],c]
// Structure is a deterministic function of L=3 -> replicated at compile time.
// R3: cg broadcast via v_readlane from 8 VGPRs (no SMEM serialization).
// R4: amdgpu_waves_per_eu(4,4) -- R3's counters showed VGPR_Count=64 with
//     WRITE_SIZE 60MB (ideal 17MB): the scheduler targeted the 8-waves/EU
//     64-VGPR tier and spilled ~20 dwords/thread to scratch. Pinning the
//     occupancy target at exactly 4 waves/EU gives a 128-VGPR budget for a
//     ~90-reg working set -> no spill.

#define LMAX 3
#define MOUT 16          // (L+1)^2
#define CCH 128          // channels
#define NTRI 34
#define NNZ 478
#define NPAIR 156        // nonempty (output-order, triple) pairs
#define NCGV 8           // ceil(NNZ/64) VGPRs holding cg per wave

struct Tables {
    int n_tri = 0;
    int nnz = 0;
    int np = 0;
    int tl[NTRI] = {}, tl1[NTRI] = {}, tl2[NTRI] = {};
    int M1[NNZ] = {}, M2[NNZ] = {};
    int pair_tri[NPAIR] = {};
    int pair_kstart[NPAIR + 1] = {};
    int mo_pstart[MOUT + 1] = {};
};

constexpr Tables build_tables() {
    Tables T{};
    // triples, insertion order == tri_index order in the reference
    for (int l1 = 0; l1 <= LMAX; ++l1) {
        for (int l2 = 0; l2 <= LMAX; ++l2) {
            int lo = l1 - l2; if (lo < 0) lo = -lo;
            int hi = l1 + l2; if (hi > LMAX) hi = LMAX;
            for (int l = lo; l <= hi; ++l) {
                T.tl[T.n_tri] = l; T.tl1[T.n_tri] = l1; T.tl2[T.n_tri] = l2;
                ++T.n_tri;
            }
        }
    }
    // rows sorted by output order Mo; entries grouped by (Mo, triple)
    for (int l = 0; l <= LMAX; ++l) {
        for (int m = -l; m <= l; ++m) {
            const int Mo = l * l + l + m;
            T.mo_pstart[Mo] = T.np;
            for (int t = 0; t < T.n_tri; ++t) {
                if (T.tl[t] != l) continue;
                const int l1 = T.tl1[t], l2 = T.tl2[t];
                int lo = (-l1 > m - l2) ? -l1 : m - l2;
                int hi = (l1 < m + l2) ? l1 : m + l2;
                if (lo > hi) continue;
                T.pair_tri[T.np] = t;
                T.pair_kstart[T.np] = T.nnz;
                ++T.np;
                for (int m1 = lo; m1 <= hi; ++m1) {
                    const int m2 = m - m1;
                    T.M1[T.nnz] = l1 * l1 + l1 + m1;
                    T.M2[T.nnz] = l2 * l2 + l2 + m2;
                    ++T.nnz;
                }
            }
        }
    }
    T.mo_pstart[MOUT] = T.np;
    T.pair_kstart[T.np] = T.nnz;
    return T;
}

constexpr Tables TB = build_tables();
static_assert(TB.nnz == NNZ, "nnz mismatch vs reference _build_structure");
static_assert(TB.n_tri == NTRI, "n_tri mismatch vs reference _build_structure");
static_assert(TB.np == NPAIR, "pair count mismatch");

__global__ __launch_bounds__(256)
__attribute__((amdgpu_waves_per_eu(4, 4)))
void wtp_kernel(const float* __restrict__ x1, const float* __restrict__ x2,
                const float* __restrict__ w, const float* __restrict__ cg,
                float* __restrict__ out, int B) {
    const int c = threadIdx.x;                              // channel 0..127
    const int lane = threadIdx.x & 63;                      // lane within wave
    const int b = blockIdx.x * blockDim.y + threadIdx.y;    // batch
    if (b >= B) return;

    // cg staged across the wave's lanes: vcg[j] lane L holds cg[j*64+L].
    // One coalesced dword load per 64 values; j=7 tail exec-masked.
    float vcg[NCGV];
#pragma unroll
    for (int j = 0; j < NCGV; ++j) {
        const int idx = j * 64 + lane;
        vcg[j] = (idx < NNZ) ? cg[idx] : 0.f;
    }

    const size_t base = (size_t)b * (MOUT * CCH) + c;
    const float* x1b = x1 + base;
    const float* x2b = x2 + base;

    // x1/x2 rows for this (b,c) into registers: coalesced dword loads per wave
    float x1r[MOUT], x2r[MOUT];
#pragma unroll
    for (int m = 0; m < MOUT; ++m) {
        x1r[m] = x1b[(size_t)m * CCH];
        x2r[m] = x2b[(size_t)m * CCH];
    }

    // all 34 per-triple weights for this channel into registers
    float wr[NTRI];
#pragma unroll
    for (int t = 0; t < NTRI; ++t) wr[t] = w[t * CCH + c];

    float* outb = out + base;
#pragma unroll
    for (int mo = 0; mo < MOUT; ++mo) {
        float acc = 0.f;
#pragma unroll
        for (int p = TB.mo_pstart[mo]; p < TB.mo_pstart[mo + 1]; ++p) {
            float inner = 0.f;
#pragma unroll
            for (int k = TB.pair_kstart[p]; k < TB.pair_kstart[p + 1]; ++k) {
                // v_readlane_b32: wave-uniform cg[k] from VGPR lane (both
                // operands compile-time constants) -> SGPR, no SMEM access.
                const float cgk = __int_as_float(
                    __builtin_amdgcn_readlane(__float_as_int(vcg[k >> 6]), k & 63));
                inner = fmaf(cgk, x1r[TB.M1[k]] * x2r[TB.M2[k]], inner);
            }
            acc = fmaf(wr[TB.pair_tri[p]], inner, acc);
        }
        outb[(size_t)mo * CCH] = acc;
    }
}

extern "C" void kernel_launch(void* const* d_in, const int* in_sizes, int n_in,
                              void* d_out, int out_size, void* d_ws, size_t ws_size,
                              hipStream_t stream) {
    const float* x1 = (const float*)d_in[0];
    const float* x2 = (const float*)d_in[1];
    const float* w  = (const float*)d_in[2];
    const float* cg = (const float*)d_in[3];
    float* out = (float*)d_out;

    const int B = in_sizes[0] / (MOUT * CCH);   // 2048

    dim3 block(CCH, 2, 1);                      // 256 threads: lane = channel
    dim3 grid((B + 1) / 2, 1, 1);
    wtp_kernel<<<grid, block, 0, stream>>>(x1, x2, w, cg, out, B);
}

// Round 5
// 102.038 us; speedup vs baseline: 1.1540x; 1.1477x over previous
//
#include <hip/hip_runtime.h>

// WeightedTensorProduct: out[b, seg[k], c] += x1[b,M1[k],c]*x2[b,M2[k],c]*CG[k]*W[l_ind[k],c]
// Structure is a deterministic function of L=3 -> replicated at compile time.
// R5: shrink per-thread register demand BELOW the 64-VGPR tier so the
//     allocator cannot spill regardless of its occupancy target:
//       - wr[34] moved to LDS (block-staged, compile-time ds_read offsets,
//         2-way bank aliasing = free)
//       - cg[k] via wave-uniform scalar loads (R1 evidence: s_load beat
//         readlane by ~18us -- scalar pipe runs parallel to VALU)
//       - factorized (mo,triple) form: ~2 VALU/entry + 156 pair FMAs
//     Working set: x1r[16]+x2r[16]+temps ~= 48 VGPR.

#define LMAX 3
#define MOUT 16          // (L+1)^2
#define CCH 128          // channels
#define NTRI 34
#define NNZ 478
#define NPAIR 156        // nonempty (output-order, triple) pairs

struct Tables {
    int n_tri = 0;
    int nnz = 0;
    int np = 0;
    int tl[NTRI] = {}, tl1[NTRI] = {}, tl2[NTRI] = {};
    int M1[NNZ] = {}, M2[NNZ] = {};
    int pair_tri[NPAIR] = {};
    int pair_kstart[NPAIR + 1] = {};
    int mo_pstart[MOUT + 1] = {};
};

constexpr Tables build_tables() {
    Tables T{};
    // triples, insertion order == tri_index order in the reference
    for (int l1 = 0; l1 <= LMAX; ++l1) {
        for (int l2 = 0; l2 <= LMAX; ++l2) {
            int lo = l1 - l2; if (lo < 0) lo = -lo;
            int hi = l1 + l2; if (hi > LMAX) hi = LMAX;
            for (int l = lo; l <= hi; ++l) {
                T.tl[T.n_tri] = l; T.tl1[T.n_tri] = l1; T.tl2[T.n_tri] = l2;
                ++T.n_tri;
            }
        }
    }
    // rows sorted by output order Mo; entries grouped by (Mo, triple)
    for (int l = 0; l <= LMAX; ++l) {
        for (int m = -l; m <= l; ++m) {
            const int Mo = l * l + l + m;
            T.mo_pstart[Mo] = T.np;
            for (int t = 0; t < T.n_tri; ++t) {
                if (T.tl[t] != l) continue;
                const int l1 = T.tl1[t], l2 = T.tl2[t];
                int lo = (-l1 > m - l2) ? -l1 : m - l2;
                int hi = (l1 < m + l2) ? l1 : m + l2;
                if (lo > hi) continue;
                T.pair_tri[T.np] = t;
                T.pair_kstart[T.np] = T.nnz;
                ++T.np;
                for (int m1 = lo; m1 <= hi; ++m1) {
                    const int m2 = m - m1;
                    T.M1[T.nnz] = l1 * l1 + l1 + m1;
                    T.M2[T.nnz] = l2 * l2 + l2 + m2;
                    ++T.nnz;
                }
            }
        }
    }
    T.mo_pstart[MOUT] = T.np;
    T.pair_kstart[T.np] = T.nnz;
    return T;
}

constexpr Tables TB = build_tables();
static_assert(TB.nnz == NNZ, "nnz mismatch vs reference _build_structure");
static_assert(TB.n_tri == NTRI, "n_tri mismatch vs reference _build_structure");
static_assert(TB.np == NPAIR, "pair count mismatch");

__global__ __launch_bounds__(256)
void wtp_kernel(const float* __restrict__ x1, const float* __restrict__ x2,
                const float* __restrict__ w, const float* __restrict__ cg,
                float* __restrict__ out, int B) {
    // per-triple weights staged in LDS: ws[t*CCH + c], 34*128*4 = 17408 B
    __shared__ float ws[NTRI * CCH];
    const int tid = threadIdx.x + CCH * threadIdx.y;    // 0..255
#pragma unroll
    for (int i = 0; i < NTRI * CCH / 256; ++i)
        ws[i * 256 + tid] = w[i * 256 + tid];
    // tail: 34*128 = 4352 = 17*256, exact -> no tail
    __syncthreads();

    const int c = threadIdx.x;                              // channel 0..127
    const int b = blockIdx.x * blockDim.y + threadIdx.y;    // batch
    if (b >= B) return;

    const size_t base = (size_t)b * (MOUT * CCH) + c;
    const float* x1b = x1 + base;
    const float* x2b = x2 + base;

    // x1/x2 rows for this (b,c) into registers: coalesced dword loads per wave
    float x1r[MOUT], x2r[MOUT];
#pragma unroll
    for (int m = 0; m < MOUT; ++m) {
        x1r[m] = x1b[(size_t)m * CCH];
        x2r[m] = x2b[(size_t)m * CCH];
    }

    const float* wsc = ws + c;   // wsc[t*CCH]: ds_read_b32 offset t*512, 2-way bank = free
    float* outb = out + base;
#pragma unroll
    for (int mo = 0; mo < MOUT; ++mo) {
        float acc = 0.f;
#pragma unroll
        for (int p = TB.mo_pstart[mo]; p < TB.mo_pstart[mo + 1]; ++p) {
            float inner = 0.f;
#pragma unroll
            for (int k = TB.pair_kstart[p]; k < TB.pair_kstart[p + 1]; ++k) {
                // cg[k]: wave-uniform, compile-time offset -> batched s_load
                // (scalar pipe, parallel to VALU)
                inner = fmaf(cg[k], x1r[TB.M1[k]] * x2r[TB.M2[k]], inner);
            }
            acc = fmaf(wsc[TB.pair_tri[p] * CCH], inner, acc);
        }
        outb[(size_t)mo * CCH] = acc;
    }
}

extern "C" void kernel_launch(void* const* d_in, const int* in_sizes, int n_in,
                              void* d_out, int out_size, void* d_ws, size_t ws_size,
                              hipStream_t stream) {
    const float* x1 = (const float*)d_in[0];
    const float* x2 = (const float*)d_in[1];
    const float* w  = (const float*)d_in[2];
    const float* cg = (const float*)d_in[3];
    float* out = (float*)d_out;

    const int B = in_sizes[0] / (MOUT * CCH);   // 2048

    dim3 block(CCH, 2, 1);                      // 256 threads: lane = channel
    dim3 grid((B + 1) / 2, 1, 1);
    wtp_kernel<<<grid, block, 0, stream>>>(x1, x2, w, cg, out, B);
}

// Round 6
// 98.394 us; speedup vs baseline: 1.1968x; 1.0370x over previous
//
#include <hip/hip_runtime.h>

// WeightedTensorProduct: out[b, seg[k], c] += x1[b,M1[k],c]*x2[b,M2[k],c]*CG[k]*W[l_ind[k],c]
// Structure is a deterministic function of L=3 -> replicated at compile time.
// R6: combine the two partial fixes, avoiding both measured failure modes:
//   - cg via v_readlane from 8 wave-staged VGPRs (NO s_load chain: R1/R5's
//     ~20us per-wave serialized SMEM latency; readlane is full-rate VALU,
//     lane+reg operands compile-time constants)
//   - w via LDS ds_read_b32 (only 156, pure-DS lgkmcnt = in-order fine waits;
//     keeps register demand at ~50 VGPR so the 64-reg tier cannot spill --
//     R3's 60MB scratch traffic)

#define LMAX 3
#define MOUT 16          // (L+1)^2
#define CCH 128          // channels
#define NTRI 34
#define NNZ 478
#define NPAIR 156        // nonempty (output-order, triple) pairs
#define NCGV 8           // ceil(NNZ/64) VGPRs holding cg per wave

struct Tables {
    int n_tri = 0;
    int nnz = 0;
    int np = 0;
    int tl[NTRI] = {}, tl1[NTRI] = {}, tl2[NTRI] = {};
    int M1[NNZ] = {}, M2[NNZ] = {};
    int pair_tri[NPAIR] = {};
    int pair_kstart[NPAIR + 1] = {};
    int mo_pstart[MOUT + 1] = {};
};

constexpr Tables build_tables() {
    Tables T{};
    // triples, insertion order == tri_index order in the reference
    for (int l1 = 0; l1 <= LMAX; ++l1) {
        for (int l2 = 0; l2 <= LMAX; ++l2) {
            int lo = l1 - l2; if (lo < 0) lo = -lo;
            int hi = l1 + l2; if (hi > LMAX) hi = LMAX;
            for (int l = lo; l <= hi; ++l) {
                T.tl[T.n_tri] = l; T.tl1[T.n_tri] = l1; T.tl2[T.n_tri] = l2;
                ++T.n_tri;
            }
        }
    }
    // rows sorted by output order Mo; entries grouped by (Mo, triple)
    for (int l = 0; l <= LMAX; ++l) {
        for (int m = -l; m <= l; ++m) {
            const int Mo = l * l + l + m;
            T.mo_pstart[Mo] = T.np;
            for (int t = 0; t < T.n_tri; ++t) {
                if (T.tl[t] != l) continue;
                const int l1 = T.tl1[t], l2 = T.tl2[t];
                int lo = (-l1 > m - l2) ? -l1 : m - l2;
                int hi = (l1 < m + l2) ? l1 : m + l2;
                if (lo > hi) continue;
                T.pair_tri[T.np] = t;
                T.pair_kstart[T.np] = T.nnz;
                ++T.np;
                for (int m1 = lo; m1 <= hi; ++m1) {
                    const int m2 = m - m1;
                    T.M1[T.nnz] = l1 * l1 + l1 + m1;
                    T.M2[T.nnz] = l2 * l2 + l2 + m2;
                    ++T.nnz;
                }
            }
        }
    }
    T.mo_pstart[MOUT] = T.np;
    T.pair_kstart[T.np] = T.nnz;
    return T;
}

constexpr Tables TB = build_tables();
static_assert(TB.nnz == NNZ, "nnz mismatch vs reference _build_structure");
static_assert(TB.n_tri == NTRI, "n_tri mismatch vs reference _build_structure");
static_assert(TB.np == NPAIR, "pair count mismatch");

__global__ __launch_bounds__(256)
void wtp_kernel(const float* __restrict__ x1, const float* __restrict__ x2,
                const float* __restrict__ w, const float* __restrict__ cg,
                float* __restrict__ out, int B) {
    // per-triple weights staged in LDS: ws[t*CCH + c], 34*128*4 = 17408 B
    __shared__ float ws[NTRI * CCH];
    const int tid = threadIdx.x + CCH * threadIdx.y;    // 0..255
#pragma unroll
    for (int i = 0; i < NTRI * CCH / 256; ++i)          // 17 iters, exact
        ws[i * 256 + tid] = w[i * 256 + tid];
    __syncthreads();

    const int c = threadIdx.x;                              // channel 0..127
    const int lane = threadIdx.x & 63;                      // lane within wave
    const int b = blockIdx.x * blockDim.y + threadIdx.y;    // batch
    if (b >= B) return;

    // cg staged across the wave's lanes: vcg[j] lane L holds cg[j*64+L].
    float vcg[NCGV];
#pragma unroll
    for (int j = 0; j < NCGV; ++j) {
        const int idx = j * 64 + lane;
        vcg[j] = (idx < NNZ) ? cg[idx] : 0.f;
    }

    const size_t base = (size_t)b * (MOUT * CCH) + c;
    const float* x1b = x1 + base;
    const float* x2b = x2 + base;

    // x1/x2 rows for this (b,c) into registers: coalesced dword loads per wave
    float x1r[MOUT], x2r[MOUT];
#pragma unroll
    for (int m = 0; m < MOUT; ++m) {
        x1r[m] = x1b[(size_t)m * CCH];
        x2r[m] = x2b[(size_t)m * CCH];
    }

    const float* wsc = ws + c;   // ds_read_b32, offset t*512, 2-way bank = free
    float* outb = out + base;
#pragma unroll
    for (int mo = 0; mo < MOUT; ++mo) {
        float acc = 0.f;
#pragma unroll
        for (int p = TB.mo_pstart[mo]; p < TB.mo_pstart[mo + 1]; ++p) {
            float inner = 0.f;
#pragma unroll
            for (int k = TB.pair_kstart[p]; k < TB.pair_kstart[p + 1]; ++k) {
                // wave-uniform cg[k]: v_readlane_b32 (VALU, const lane) -> SGPR
                const float cgk = __int_as_float(
                    __builtin_amdgcn_readlane(__float_as_int(vcg[k >> 6]), k & 63));
                inner = fmaf(cgk, x1r[TB.M1[k]] * x2r[TB.M2[k]], inner);
            }
            acc = fmaf(wsc[TB.pair_tri[p] * CCH], inner, acc);
        }
        outb[(size_t)mo * CCH] = acc;
    }
}

extern "C" void kernel_launch(void* const* d_in, const int* in_sizes, int n_in,
                              void* d_out, int out_size, void* d_ws, size_t ws_size,
                              hipStream_t stream) {
    const float* x1 = (const float*)d_in[0];
    const float* x2 = (const float*)d_in[1];
    const float* w  = (const float*)d_in[2];
    const float* cg = (const float*)d_in[3];
    float* out = (float*)d_out;

    const int B = in_sizes[0] / (MOUT * CCH);   // 2048

    dim3 block(CCH, 2, 1);                      // 256 threads: lane = channel
    dim3 grid((B + 1) / 2, 1, 1);
    wtp_kernel<<<grid, block, 0, stream>>>(x1, x2, w, cg, out, B);
}